// Round 2
// baseline (769.652 us; speedup 1.0000x reference)
//
#include <hip/hip_runtime.h>

constexpr int N_ENTITIES = 100000;
constexpr int N_USERS    = 50000;
constexpr int N_FACTORS  = 4;
constexpr int N_META     = 8;
constexpr int CHANNEL    = 64;
constexpr int N_EDGES    = 1600000;
constexpr int NNZ        = 1000000;

__device__ __forceinline__ float wave_reduce_sum(float v) {
    // full 64-lane butterfly
    for (int off = 32; off > 0; off >>= 1)
        v += __shfl_xor(v, off, 64);
    return v;
}

// One wave per edge (lane = channel). Coalesced 256B row accesses.
__global__ void edge_kernel(const float* __restrict__ entity_emb,
                            const int*   __restrict__ head,
                            const int*   __restrict__ tail,
                            const int*   __restrict__ etype,
                            const float* __restrict__ rel_w,   // (31, 64)
                            float*       __restrict__ ent_acc, // (N_ENTITIES, 64)
                            float*       __restrict__ cnt) {   // (N_ENTITIES)
    const int lane = threadIdx.x & 63;
    const int wid  = (blockIdx.x * blockDim.x + threadIdx.x) >> 6;
    const int nw   = (gridDim.x * blockDim.x) >> 6;
    for (int e = wid; e < N_EDGES; e += nw) {
        const int h = head[e];
        const int t = tail[e];
        const int r = etype[e] - 1;
        const float rw = rel_w[r * CHANNEL + lane];
        const float eh = entity_emb[h * CHANNEL + lane];
        const float dot = wave_reduce_sum(eh * rw);
        const float att = 1.0f / (1.0f + expf(-dot));
        const float et  = entity_emb[t * CHANNEL + lane];
        atomicAdd(&ent_acc[h * CHANNEL + lane], att * et * rw);
        if (lane == 0) atomicAdd(&cnt[h], 1.0f);
    }
}

// One wave per nonzero: user_acc[row] += val * entity_emb[col]
__global__ void spmm_kernel(const float* __restrict__ entity_emb,
                            const int*   __restrict__ mat_row,
                            const int*   __restrict__ mat_col,
                            const float* __restrict__ mat_val,
                            float*       __restrict__ user_acc) { // (N_USERS, 64)
    const int lane = threadIdx.x & 63;
    const int wid  = (blockIdx.x * blockDim.x + threadIdx.x) >> 6;
    const int nw   = (gridDim.x * blockDim.x) >> 6;
    for (int i = wid; i < NNZ; i += nw) {
        const int r   = mat_row[i];
        const int c   = mat_col[i];
        const float v = mat_val[i];
        const float e = entity_emb[c * CHANNEL + lane];
        atomicAdd(&user_acc[r * CHANNEL + lane], v * e);
    }
}

// entity_agg = acc / max(cnt, 1)  (in place, float4)
__global__ void ent_final_kernel(float* __restrict__ ent,
                                 const float* __restrict__ cnt) {
    const int total = N_ENTITIES * (CHANNEL / 4);
    for (int i = blockIdx.x * blockDim.x + threadIdx.x; i < total;
         i += gridDim.x * blockDim.x) {
        const int row = i >> 4;                 // 16 float4 per row
        const float inv = 1.0f / fmaxf(cnt[row], 1.0f);
        float4 v = reinterpret_cast<float4*>(ent)[i];
        v.x *= inv; v.y *= inv; v.z *= inv; v.w *= inv;
        reinterpret_cast<float4*>(ent)[i] = v;
    }
}

// user_out = acc * (1 + sum_f score[u,f] * disen_weight[f,:])  (in place)
__global__ void user_final_kernel(const float* __restrict__ user_emb,
                                  const float* __restrict__ latent_emb, // (4,64)
                                  const float* __restrict__ weight,     // (8,64)
                                  const float* __restrict__ datt,       // (4,8)
                                  float*       __restrict__ user_out) {
    __shared__ float dw[N_FACTORS][CHANNEL];
    const int tid = threadIdx.x;
    // per-block redundant compute of disen_weight = softmax(datt, -1) @ weight
    if (tid < N_FACTORS * CHANNEL) {
        const int f = tid >> 6, c = tid & 63;
        float m = -1e30f;
        for (int j = 0; j < N_META; ++j) m = fmaxf(m, datt[f * N_META + j]);
        float p[N_META]; float s = 0.0f;
        for (int j = 0; j < N_META; ++j) { p[j] = expf(datt[f * N_META + j] - m); s += p[j]; }
        const float invs = 1.0f / s;
        float acc = 0.0f;
        for (int j = 0; j < N_META; ++j) acc += p[j] * invs * weight[j * CHANNEL + c];
        dw[f][c] = acc;
    }
    __syncthreads();

    const int lane = tid & 63;
    const int wib  = tid >> 6;
    const int wpb  = blockDim.x >> 6;
    for (int u = blockIdx.x * wpb + wib; u < N_USERS; u += gridDim.x * wpb) {
        const float ue = user_emb[u * CHANNEL + lane];
        float d0 = wave_reduce_sum(ue * latent_emb[0 * CHANNEL + lane]);
        float d1 = wave_reduce_sum(ue * latent_emb[1 * CHANNEL + lane]);
        float d2 = wave_reduce_sum(ue * latent_emb[2 * CHANNEL + lane]);
        float d3 = wave_reduce_sum(ue * latent_emb[3 * CHANNEL + lane]);
        const float m = fmaxf(fmaxf(d0, d1), fmaxf(d2, d3));
        d0 = expf(d0 - m); d1 = expf(d1 - m); d2 = expf(d2 - m); d3 = expf(d3 - m);
        const float invs = 1.0f / (d0 + d1 + d2 + d3);
        const float g = (d0 * dw[0][lane] + d1 * dw[1][lane] +
                         d2 * dw[2][lane] + d3 * dw[3][lane]) * invs;
        const float a = user_out[u * CHANNEL + lane];
        user_out[u * CHANNEL + lane] = a * (1.0f + g);
    }
}

extern "C" void kernel_launch(void* const* d_in, const int* in_sizes, int n_in,
                              void* d_out, int out_size, void* d_ws, size_t ws_size,
                              hipStream_t stream) {
    const float* entity_emb = (const float*)d_in[0];
    const float* user_emb   = (const float*)d_in[1];
    const float* latent_emb = (const float*)d_in[2];
    const int*   head       = (const int*)d_in[3];
    const int*   tail       = (const int*)d_in[4];
    const int*   etype      = (const int*)d_in[5];
    const int*   mat_row    = (const int*)d_in[6];
    const int*   mat_col    = (const int*)d_in[7];
    const float* mat_val    = (const float*)d_in[8];
    const float* rel_w      = (const float*)d_in[9];
    const float* weight     = (const float*)d_in[10];
    const float* datt       = (const float*)d_in[11];

    float* out      = (float*)d_out;
    float* ent_acc  = out;                              // N_ENTITIES*64
    float* user_acc = out + (size_t)N_ENTITIES * CHANNEL; // N_USERS*64
    float* cnt      = (float*)d_ws;                     // N_ENTITIES floats

    hipMemsetAsync(d_out, 0, (size_t)out_size * sizeof(float), stream);
    hipMemsetAsync(d_ws, 0, (size_t)N_ENTITIES * sizeof(float), stream);

    edge_kernel<<<4096, 256, 0, stream>>>(entity_emb, head, tail, etype, rel_w,
                                          ent_acc, cnt);
    spmm_kernel<<<4096, 256, 0, stream>>>(entity_emb, mat_row, mat_col, mat_val,
                                          user_acc);
    ent_final_kernel<<<2048, 256, 0, stream>>>(ent_acc, cnt);
    user_final_kernel<<<1024, 256, 0, stream>>>(user_emb, latent_emb, weight,
                                                datt, user_acc);
}